// Round 3
// baseline (138.532 us; speedup 1.0000x reference)
//
#include <hip/hip_runtime.h>
#include <stdint.h>

typedef int i32x4 __attribute__((ext_vector_type(4)));

#define N_IMG 32
#define C_IN 256
#define H_IN 56
#define W_IN 56
#define K_OUT 256
#define H_OUT 54
#define W_OUT 54
#define HW_OUT 2916          // 54*54
#define M_PIX 93312          // 32*2916 = 729 * 128
#define CHW_OUT 746496       // 256*2916

#define XT_BYTES ((size_t)N_IMG * H_IN * W_IN * C_IN)   // 25,690,112 (i8 NHWC)
#define WT_BYTES ((size_t)9 * K_OUT * C_IN)             // 589,824   (i8 [rs][k][c])

// -------- transform 1: x NCHW int32 -> NHWC i8 (clip to 0..7, exact) --------
__global__ __launch_bounds__(256) void xform_x(const int* __restrict__ x,
                                               unsigned char* __restrict__ xt) {
    const int bid = blockIdx.x;          // n*56 + h
    const int n = bid / H_IN;
    const int h = bid % H_IN;
    const int c = threadIdx.x;
    const int* src = x + ((size_t)((n * C_IN + c) * H_IN + h)) * W_IN;
    unsigned char* dst = xt + ((size_t)(n * H_IN + h) * W_IN) * C_IN + c;
    #pragma unroll
    for (int w0 = 0; w0 < W_IN; w0 += 4) {
        int4 v = *(const int4*)(src + w0);
        int a[4] = {v.x, v.y, v.z, v.w};
        #pragma unroll
        for (int j = 0; j < 4; ++j) {
            int q = a[j] < 0 ? 0 : (a[j] > 7 ? 7 : a[j]);
            dst[(size_t)(w0 + j) * C_IN] = (unsigned char)q;
        }
    }
}

// -------- transform 2: weight OIHW fp32 -> [rs][k][c] i8 (trunc to int) --------
__global__ __launch_bounds__(256) void xform_w(const float* __restrict__ w,
                                               unsigned char* __restrict__ wt) {
    const int k = blockIdx.x;
    const int c = threadIdx.x;
    const float* src = w + ((size_t)k * C_IN + c) * 9;
    #pragma unroll
    for (int rs = 0; rs < 9; ++rs) {
        int iv = (int)src[rs];   // truncation == astype(int32); values 0..6
        wt[((size_t)rs * K_OUT + k) * C_IN + c] = (unsigned char)iv;
    }
}

// -------- async global->LDS (width 16) --------
__device__ __forceinline__ void gload_lds16(const void* g, void* l) {
    __builtin_amdgcn_global_load_lds(
        (const __attribute__((address_space(1))) uint32_t*)g,
        (__attribute__((address_space(3))) uint32_t*)l,
        16, 0, 0);
}

__device__ __forceinline__ unsigned lds_off(const void* p) {
    return (unsigned)(unsigned long long)(__attribute__((address_space(3))) const char*)p;
}

#define DSREAD(dst, addr) \
    asm volatile("ds_read_b128 %0, %1" : "=v"(dst) : "v"(addr))
#define WAIT_LGKM0 asm volatile("s_waitcnt lgkmcnt(0)" ::: "memory")

// One K-step: compute from (CA,CB), optionally prefetch step T+2 into (PA,PB).
// VM: 6 = counted steady-state wait, 0 = tail drain, -1 = none (last step).
template <bool PRE, int VM>
__device__ __forceinline__ void kstep(int T, unsigned CA, unsigned CB,
                                      unsigned char* PA, unsigned char* PB,
                                      const char* xb, const char* wb,
                                      const int* abase, const int* bbase,
                                      const unsigned (&aoff)[4][2],
                                      const unsigned (&boff)[4][2],
                                      int tb16, i32x4 (&acc)[4][4]) {
    int astp = 0, bstp = 0;
    if constexpr (PRE) {
        const int tp = T + 2;
        const int rp = tp >> 1, cp = (tp & 1) << 7;
        const int rr = rp / 3, ss = rp - rr * 3;
        astp = ((rr * W_IN + ss) << 8) + cp;
        bstp = rp * (K_OUT * C_IN) + cp;
    }
    i32x4 af[4][2], bf[4][2];
    // ---------------- phase 1: all A frags + B frags 0,1 ----------------
    #pragma unroll
    for (int mf = 0; mf < 4; ++mf)
        #pragma unroll
        for (int kk = 0; kk < 2; ++kk)
            DSREAD(af[mf][kk], CA + aoff[mf][kk]);
    #pragma unroll
    for (int nf = 0; nf < 2; ++nf)
        #pragma unroll
        for (int kk = 0; kk < 2; ++kk)
            DSREAD(bf[nf][kk], CB + boff[nf][kk]);
    if constexpr (PRE) {
        gload_lds16(xb + abase[0] + astp, PA + tb16);
        gload_lds16(xb + abase[1] + astp, PA + 8192 + tb16);
        gload_lds16(wb + bbase[0] + bstp, PB + tb16);
    }
    __builtin_amdgcn_s_barrier();
    WAIT_LGKM0;
    __builtin_amdgcn_sched_barrier(0);
    __builtin_amdgcn_s_setprio(1);
    #pragma unroll
    for (int mf = 0; mf < 4; ++mf)
        #pragma unroll
        for (int nf = 0; nf < 2; ++nf)
            #pragma unroll
            for (int kk = 0; kk < 2; ++kk)
                acc[mf][nf] = __builtin_amdgcn_mfma_i32_16x16x64_i8(
                    af[mf][kk], bf[nf][kk], acc[mf][nf], 0, 0, 0);
    __builtin_amdgcn_s_setprio(0);
    __builtin_amdgcn_s_barrier();
    // ---------------- phase 2: B frags 2,3 ----------------
    #pragma unroll
    for (int nf = 2; nf < 4; ++nf)
        #pragma unroll
        for (int kk = 0; kk < 2; ++kk)
            DSREAD(bf[nf][kk], CB + boff[nf][kk]);
    if constexpr (PRE) {
        gload_lds16(wb + bbase[1] + bstp, PB + 8192 + tb16);
        gload_lds16(wb + bbase[2] + bstp, PB + 16384 + tb16);
        gload_lds16(wb + bbase[3] + bstp, PB + 24576 + tb16);
    }
    __builtin_amdgcn_s_barrier();
    WAIT_LGKM0;
    __builtin_amdgcn_sched_barrier(0);
    __builtin_amdgcn_s_setprio(1);
    #pragma unroll
    for (int mf = 0; mf < 4; ++mf)
        #pragma unroll
        for (int nf = 2; nf < 4; ++nf)
            #pragma unroll
            for (int kk = 0; kk < 2; ++kk)
                acc[mf][nf] = __builtin_amdgcn_mfma_i32_16x16x64_i8(
                    af[mf][kk], bf[nf][kk], acc[mf][nf], 0, 0, 0);
    __builtin_amdgcn_s_setprio(0);
    if constexpr (VM == 6) asm volatile("s_waitcnt vmcnt(6)" ::: "memory");
    else if constexpr (VM == 0) asm volatile("s_waitcnt vmcnt(0)" ::: "memory");
    if constexpr (VM >= 0) __builtin_amdgcn_s_barrier();
}

// -------- main conv (i8, 8-wave, counted-vmcnt pipeline) --------
// BM=128 pixels, BN=256 out-ch, BK=128 in-ch; 18 K-steps (9 taps x 2 halves).
__global__ __launch_bounds__(512, 2) void conv_mfma(const unsigned char* __restrict__ xt,
                                                    const unsigned char* __restrict__ wt,
                                                    float* __restrict__ out) {
    __shared__ __align__(16) unsigned char As[3 * 16384];   // 48 KiB: 3 x [128pix][128c]
    __shared__ __align__(16) unsigned char Bs[3 * 32768];   // 96 KiB: 3 x [256ch][128c]

    const int t512 = threadIdx.x;
    const int l    = t512 & 63;
    const int wid  = t512 >> 6;
    const int wr   = wid >> 2;     // 0..1 -> 64-pixel half
    const int wc   = wid & 3;      // 0..3 -> 64-channel quarter
    const int mb   = blockIdx.x;   // 729 M-tiles

    // ---- staging geometry: 512 threads x 16 B = 8192 B / round ----
    // round covers 64 rows of 128 B; thread t: row = t>>3, slot = t&7.
    // Both-sides swizzle: LDS slot s of row r holds data chunk s^(r&7).
    const int srow = t512 >> 3;
    const int cs   = (((t512 & 7) ^ (srow & 7)) << 4);
    const int tb16 = t512 * 16;

    int abase[2], bbase[4];
    #pragma unroll
    for (int i = 0; i < 2; ++i) {
        const int m   = mb * 128 + i * 64 + srow;
        const int n   = m / HW_OUT;
        const int rem = m - n * HW_OUT;
        const int ho  = rem / W_OUT;
        const int wo  = rem - ho * W_OUT;
        abase[i] = (((n * H_IN + ho) * W_IN + wo) << 8) + cs;   // 256 B per NHWC pixel
    }
    #pragma unroll
    for (int j = 0; j < 4; ++j)
        bbase[j] = ((j * 64 + srow) << 8) + cs;                 // 256 B per k-row

    // ---- per-wave fragment read offsets (loop-invariant) ----
    const int lrow = l & 15;
    const int lkb  = (l >> 4) << 4;                 // 0/16/32/48
    const unsigned swz = (unsigned)((lrow & 7) << 4);
    unsigned aoff[4][2], boff[4][2];
    #pragma unroll
    for (int f = 0; f < 4; ++f)
        #pragma unroll
        for (int kk = 0; kk < 2; ++kk) {
            const unsigned kb = (unsigned)(((kk << 6) + lkb)) ^ swz;
            aoff[f][kk] = (unsigned)(((wr * 64 + f * 16 + lrow) << 7)) + kb;
            boff[f][kk] = (unsigned)(((wc * 64 + f * 16 + lrow) << 7)) + kb;
        }

    i32x4 acc[4][4];
    #pragma unroll
    for (int i = 0; i < 4; ++i)
        #pragma unroll
        for (int j = 0; j < 4; ++j)
            acc[i][j] = (i32x4){0, 0, 0, 0};

    const char* xb = (const char*)xt;
    const char* wb = (const char*)wt;
    unsigned char* A0p = As;
    unsigned char* A1p = As + 16384;
    unsigned char* A2p = As + 32768;
    unsigned char* B0p = Bs;
    unsigned char* B1p = Bs + 32768;
    unsigned char* B2p = Bs + 65536;
    const unsigned a0 = lds_off(A0p), a1 = a0 + 16384, a2 = a0 + 32768;
    const unsigned b0 = lds_off(B0p), b1 = b0 + 32768, b2 = b0 + 65536;

    // ---- prologue: stage steps 0 and 1 (6 loads each) ----
    #define STAGE6(T, PA, PB) do {                                         \
        const int rp_ = (T) >> 1, cp_ = ((T) & 1) << 7;                    \
        const int rr_ = rp_ / 3, ss_ = rp_ - rr_ * 3;                      \
        const int ast_ = ((rr_ * W_IN + ss_) << 8) + cp_;                  \
        const int bst_ = rp_ * (K_OUT * C_IN) + cp_;                       \
        gload_lds16(xb + abase[0] + ast_, (PA) + tb16);                    \
        gload_lds16(xb + abase[1] + ast_, (PA) + 8192 + tb16);             \
        gload_lds16(wb + bbase[0] + bst_, (PB) + tb16);                    \
        gload_lds16(wb + bbase[1] + bst_, (PB) + 8192 + tb16);             \
        gload_lds16(wb + bbase[2] + bst_, (PB) + 16384 + tb16);            \
        gload_lds16(wb + bbase[3] + bst_, (PB) + 24576 + tb16);            \
    } while (0)

    STAGE6(0, A0p, B0p);
    STAGE6(1, A1p, B1p);
    asm volatile("s_waitcnt vmcnt(6)" ::: "memory");   // step-0 tiles resident
    __builtin_amdgcn_s_barrier();

    // ---- main loop: steps 0..14 (buffer cycle period 3), then 15,16,17 ----
    for (int tb = 0; tb < 15; tb += 3) {
        kstep<true, 6>(tb + 0, a0, b0, A2p, B2p, xb, wb, abase, bbase, aoff, boff, tb16, acc);
        kstep<true, 6>(tb + 1, a1, b1, A0p, B0p, xb, wb, abase, bbase, aoff, boff, tb16, acc);
        kstep<true, 6>(tb + 2, a2, b2, A1p, B1p, xb, wb, abase, bbase, aoff, boff, tb16, acc);
    }
    kstep<true, 6>(15, a0, b0, A2p, B2p, xb, wb, abase, bbase, aoff, boff, tb16, acc);
    kstep<false, 0>(16, a1, b1, A2p, B2p, xb, wb, abase, bbase, aoff, boff, tb16, acc);
    kstep<false, -1>(17, a2, b2, A2p, B2p, xb, wb, abase, bbase, aoff, boff, tb16, acc);

    // ---- epilogue: C/D layout col=lane&15, row=(lane>>4)*4+reg ----
    const int c16 = l & 15;
    const int p4  = (l >> 4) << 2;
    #pragma unroll
    for (int mf = 0; mf < 4; ++mf) {
        #pragma unroll
        for (int j = 0; j < 4; ++j) {
            const int m   = mb * 128 + wr * 64 + mf * 16 + p4 + j;
            const int n   = m / HW_OUT;
            const int rem = m - n * HW_OUT;
            float* obase = out + (size_t)n * CHW_OUT + rem;
            #pragma unroll
            for (int nf = 0; nf < 4; ++nf) {
                const int ch = wc * 64 + nf * 16 + c16;
                obase[(size_t)ch * HW_OUT] = (float)acc[mf][nf][j];
            }
        }
    }
    #undef STAGE6
}

// -------- fallback (only if ws too small): naive direct conv, exact --------
__global__ __launch_bounds__(256) void conv_naive(const int* __restrict__ x,
                                                  const float* __restrict__ w,
                                                  float* __restrict__ out) {
    int idx = blockIdx.x * 256 + threadIdx.x;
    if (idx >= N_IMG * K_OUT * HW_OUT) return;
    const int wo = idx % W_OUT;
    int tmp = idx / W_OUT;
    const int ho = tmp % H_OUT; tmp /= H_OUT;
    const int k = tmp % K_OUT;
    const int n = tmp / K_OUT;
    float acc = 0.f;
    for (int c = 0; c < C_IN; ++c) {
        const int* xp = x + ((size_t)((n * C_IN + c) * H_IN + ho)) * W_IN + wo;
        const float* wp = w + ((size_t)(k * C_IN + c)) * 9;
        #pragma unroll
        for (int r = 0; r < 3; ++r)
            #pragma unroll
            for (int s = 0; s < 3; ++s) {
                int xv = xp[r * W_IN + s];
                xv = xv < 0 ? 0 : (xv > 7 ? 7 : xv);
                acc += (float)xv * (float)(int)wp[r * 3 + s];
            }
    }
    out[idx] = acc;
}

extern "C" void kernel_launch(void* const* d_in, const int* in_sizes, int n_in,
                              void* d_out, int out_size, void* d_ws, size_t ws_size,
                              hipStream_t stream) {
    const int*   x = (const int*)d_in[0];
    const float* w = (const float*)d_in[1];
    float* out = (float*)d_out;

    const size_t need = XT_BYTES + WT_BYTES;   // ~26.3 MB
    if (ws_size >= need) {
        unsigned char* xt = (unsigned char*)d_ws;
        unsigned char* wt = (unsigned char*)((char*)d_ws + XT_BYTES);
        hipLaunchKernelGGL(xform_x, dim3(N_IMG * H_IN), dim3(256), 0, stream, x, xt);
        hipLaunchKernelGGL(xform_w, dim3(K_OUT), dim3(256), 0, stream, w, wt);
        hipLaunchKernelGGL(conv_mfma, dim3(M_PIX / 128), dim3(512), 0, stream, xt, wt, out);
    } else {
        const int total = N_IMG * K_OUT * HW_OUT;
        hipLaunchKernelGGL(conv_naive, dim3((total + 255) / 256), dim3(256), 0, stream, x, w, out);
    }
}

// Round 4
// 88.985 us; speedup vs baseline: 1.5568x; 1.5568x over previous
//
#include <hip/hip_runtime.h>
#include <stdint.h>

typedef int i32x4 __attribute__((ext_vector_type(4)));
typedef float f32x4 __attribute__((ext_vector_type(4)));

#define N_IMG 32
#define C_IN 256
#define H_IN 56
#define W_IN 56
#define K_OUT 256
#define H_OUT 54
#define W_OUT 54
#define HW_OUT 2916          // 54*54
#define M_PIX 93312          // 32*2916 = 192 * 486
#define CHW_OUT 746496       // 256*2916

#define BM 192               // pixel rows per block (M_PIX/BM = 486 exact)
#define NSTEP 18             // 9 taps x 2 c-halves (BK=128 i8)

#define XT_BYTES ((size_t)N_IMG * H_IN * W_IN * C_IN)   // 25,690,112 (i8 NHWC)
#define WT_BYTES ((size_t)9 * K_OUT * C_IN)             // 589,824   (i8 [rs][k][c])

// LDS: A0 @0 (24KB), A1 @24576, B0 @49152 (32KB), B1 @81920 -> 114688 B total
#define A_OFF1 24576
#define B_OFF0 49152
#define B_STRIDE 32768

// -------- fused transforms: x NCHW i32 -> NHWC i8 ; w OIHW f32 -> [rs][k][c] i8 ----
__global__ __launch_bounds__(256) void xform(const int* __restrict__ x,
                                             const float* __restrict__ w,
                                             unsigned char* __restrict__ xt,
                                             unsigned char* __restrict__ wt) {
    const int bid = blockIdx.x;
    if (bid < N_IMG * H_IN) {
        const int n = bid / H_IN;
        const int h = bid % H_IN;
        const int c = threadIdx.x;
        const int* src = x + ((size_t)((n * C_IN + c) * H_IN + h)) * W_IN;
        unsigned char* dst = xt + ((size_t)(n * H_IN + h) * W_IN) * C_IN + c;
        #pragma unroll
        for (int w0 = 0; w0 < W_IN; w0 += 4) {
            int4 v = *(const int4*)(src + w0);
            int a[4] = {v.x, v.y, v.z, v.w};
            #pragma unroll
            for (int j = 0; j < 4; ++j) {
                int q = a[j] < 0 ? 0 : (a[j] > 7 ? 7 : a[j]);
                dst[(size_t)(w0 + j) * C_IN] = (unsigned char)q;
            }
        }
    } else {
        const int k = bid - N_IMG * H_IN;
        const int c = threadIdx.x;
        const float* src = w + ((size_t)k * C_IN + c) * 9;
        #pragma unroll
        for (int rs = 0; rs < 9; ++rs) {
            int iv = (int)src[rs];   // truncation == astype(int32); values 0..6
            wt[((size_t)rs * K_OUT + k) * C_IN + c] = (unsigned char)iv;
        }
    }
}

// -------- async global->LDS (width 16) --------
__device__ __forceinline__ void gload_lds16(const void* g, void* l) {
    __builtin_amdgcn_global_load_lds(
        (const __attribute__((address_space(1))) uint32_t*)g,
        (__attribute__((address_space(3))) uint32_t*)l,
        16, 0, 0);
}

__device__ __forceinline__ unsigned lds_off(const void* p) {
    return (unsigned)(unsigned long long)(__attribute__((address_space(3))) const char*)p;
}

#define DSREAD(dst, addr) \
    asm volatile("ds_read_b128 %0, %1" : "=v"(dst) : "v"(addr))

// -------- main conv (i8): BM=192 pix, BN=256 ch, BK=128 c; 8 waves of 96x64 --------
__global__ __launch_bounds__(512, 2) void conv_mfma(const unsigned char* __restrict__ xt,
                                                    const unsigned char* __restrict__ wt,
                                                    float* __restrict__ out) {
    __shared__ __align__(16) unsigned char lds[114688];

    const int t512 = threadIdx.x;
    const int l    = t512 & 63;
    const int wid  = t512 >> 6;
    const int wr   = wid >> 2;     // 0..1 -> 96-pixel half
    const int wc   = wid & 3;      // 0..3 -> 64-channel quarter
    const int mb   = blockIdx.x;   // 486 M-tiles

    // ---- staging: 512 thr x 16B = 8 KB/round (64 rows of 128 B) ----
    // thread t: row = t>>3 (+64*i), slot = t&7. Both-sides swizzle:
    // LDS slot s of row r holds data chunk s^(r&7); r&7 == (t>>3)&7.
    const int srow = t512 >> 3;
    const int cs   = (((t512 & 7) ^ (srow & 7)) << 4);
    const int tb16 = t512 * 16;

    int abase[3], bbase[4];
    #pragma unroll
    for (int i = 0; i < 3; ++i) {
        const int m   = mb * BM + i * 64 + srow;
        const int n   = m / HW_OUT;
        const int rem = m - n * HW_OUT;
        const int ho  = rem / W_OUT;
        const int wo  = rem - ho * W_OUT;
        abase[i] = (((n * H_IN + ho) * W_IN + wo) << 8) + cs;   // 256 B/NHWC pixel
    }
    #pragma unroll
    for (int j = 0; j < 4; ++j)
        bbase[j] = ((j * 64 + srow) << 8) + cs;                 // 256 B/k-row

    // ---- per-wave fragment addressing ----
    const int lrow = l & 15;
    const int lk   = (l >> 4) << 4;                 // 0/16/32/48
    const unsigned swz = (unsigned)((lrow & 7) << 4);
    const unsigned colk[2] = { ((unsigned)lk) ^ swz, ((unsigned)(64 + lk)) ^ swz };
    unsigned arow128[6], brow128[4];
    #pragma unroll
    for (int mf = 0; mf < 6; ++mf) arow128[mf] = (unsigned)((wr * 96 + mf * 16 + lrow) << 7);
    #pragma unroll
    for (int nf = 0; nf < 4; ++nf) brow128[nf] = (unsigned)((wc * 64 + nf * 16 + lrow) << 7);

    i32x4 acc[6][4];
    #pragma unroll
    for (int i = 0; i < 6; ++i)
        #pragma unroll
        for (int j = 0; j < 4; ++j)
            acc[i][j] = (i32x4){0, 0, 0, 0};

    const char* xb = (const char*)xt;
    const char* wb = (const char*)wt;
    const unsigned ldsb = lds_off(lds);

    #define STAGE(T, SEL) do {                                              \
        const int rs_ = (T) >> 1, ch_ = ((T) & 1) << 7;                     \
        const int r_ = rs_ / 3, s_ = rs_ - r_ * 3;                          \
        const int ast_ = ((r_ * W_IN + s_) << 8) + ch_;                     \
        const int bst_ = rs_ * (K_OUT * C_IN) + ch_;                        \
        unsigned char* pa_ = lds + (SEL) * A_OFF1 + tb16;                   \
        unsigned char* pb_ = lds + B_OFF0 + (SEL) * B_STRIDE + tb16;        \
        gload_lds16(xb + abase[0] + ast_, pa_);                             \
        gload_lds16(xb + abase[1] + ast_, pa_ + 8192);                      \
        gload_lds16(xb + abase[2] + ast_, pa_ + 16384);                     \
        gload_lds16(wb + bbase[0] + bst_, pb_);                             \
        gload_lds16(wb + bbase[1] + bst_, pb_ + 8192);                      \
        gload_lds16(wb + bbase[2] + bst_, pb_ + 16384);                     \
        gload_lds16(wb + bbase[3] + bst_, pb_ + 24576);                     \
    } while (0)

    // one K-step: ds_read both k-chunks (+stage next), two 24-MFMA phases
    #define KBODY(CUR, DO_STAGE, TN) do {                                   \
        const unsigned aB = ldsb + (CUR) * A_OFF1;                          \
        const unsigned bB = ldsb + B_OFF0 + (CUR) * B_STRIDE;               \
        i32x4 a0[6], b0[4], a1[6], b1[4];                                   \
        _Pragma("unroll")                                                   \
        for (int mf = 0; mf < 6; ++mf) DSREAD(a0[mf], aB + arow128[mf] + colk[0]); \
        _Pragma("unroll")                                                   \
        for (int nf = 0; nf < 4; ++nf) DSREAD(b0[nf], bB + brow128[nf] + colk[0]); \
        if (DO_STAGE) STAGE(TN, ((TN) & 1));                                \
        _Pragma("unroll")                                                   \
        for (int mf = 0; mf < 6; ++mf) DSREAD(a1[mf], aB + arow128[mf] + colk[1]); \
        _Pragma("unroll")                                                   \
        for (int nf = 0; nf < 4; ++nf) DSREAD(b1[nf], bB + brow128[nf] + colk[1]); \
        asm volatile("s_waitcnt lgkmcnt(10)" ::: "memory");                 \
        __builtin_amdgcn_sched_barrier(0);                                  \
        __builtin_amdgcn_s_setprio(1);                                      \
        _Pragma("unroll")                                                   \
        for (int mf = 0; mf < 6; ++mf)                                      \
            _Pragma("unroll")                                               \
            for (int nf = 0; nf < 4; ++nf)                                  \
                acc[mf][nf] = __builtin_amdgcn_mfma_i32_16x16x64_i8(        \
                    a0[mf], b0[nf], acc[mf][nf], 0, 0, 0);                  \
        __builtin_amdgcn_s_setprio(0);                                      \
        asm volatile("s_waitcnt lgkmcnt(0)" ::: "memory");                  \
        __builtin_amdgcn_sched_barrier(0);                                  \
        __builtin_amdgcn_s_setprio(1);                                      \
        _Pragma("unroll")                                                   \
        for (int mf = 0; mf < 6; ++mf)                                      \
            _Pragma("unroll")                                               \
            for (int nf = 0; nf < 4; ++nf)                                  \
                acc[mf][nf] = __builtin_amdgcn_mfma_i32_16x16x64_i8(        \
                    a1[mf], b1[nf], acc[mf][nf], 0, 0, 0);                  \
        __builtin_amdgcn_s_setprio(0);                                      \
    } while (0)

    // ---- prologue: stage step 0 into buf 0 ----
    STAGE(0, 0);
    asm volatile("s_waitcnt vmcnt(0)" ::: "memory");
    __builtin_amdgcn_s_barrier();

    // ---- steps 0..16: compute cur, stage next; step 17: compute only ----
    for (int t = 0; t < NSTEP - 1; ++t) {
        KBODY((t & 1), 1, (t + 1));
        asm volatile("s_waitcnt vmcnt(0)" ::: "memory");
        __builtin_amdgcn_s_barrier();
    }
    KBODY(((NSTEP - 1) & 1), 0, 0);

    // ---- epilogue: C/D col=lane&15, row=(lane>>4)*4+reg; float4 stores ----
    // (2916 % 4 == 0 so each 4-dword group never straddles an image boundary)
    const int c16 = l & 15;
    const int p4  = (l >> 4) << 2;
    #pragma unroll
    for (int mf = 0; mf < 6; ++mf) {
        const int m   = mb * BM + wr * 96 + mf * 16 + p4;
        const int n   = m / HW_OUT;
        const int rem = m - n * HW_OUT;
        float* ob = out + (size_t)n * CHW_OUT + rem;
        #pragma unroll
        for (int nf = 0; nf < 4; ++nf) {
            const int ch = wc * 64 + nf * 16 + c16;
            f32x4 v;
            #pragma unroll
            for (int j = 0; j < 4; ++j) v[j] = (float)acc[mf][nf][j];
            *(f32x4*)(ob + (size_t)ch * HW_OUT) = v;
        }
    }
    #undef KBODY
    #undef STAGE
}

// -------- fallback (only if ws too small): naive direct conv, exact --------
__global__ __launch_bounds__(256) void conv_naive(const int* __restrict__ x,
                                                  const float* __restrict__ w,
                                                  float* __restrict__ out) {
    int idx = blockIdx.x * 256 + threadIdx.x;
    if (idx >= N_IMG * K_OUT * HW_OUT) return;
    const int wo = idx % W_OUT;
    int tmp = idx / W_OUT;
    const int ho = tmp % H_OUT; tmp /= H_OUT;
    const int k = tmp % K_OUT;
    const int n = tmp / K_OUT;
    float acc = 0.f;
    for (int c = 0; c < C_IN; ++c) {
        const int* xp = x + ((size_t)((n * C_IN + c) * H_IN + ho)) * W_IN + wo;
        const float* wp = w + ((size_t)(k * C_IN + c)) * 9;
        #pragma unroll
        for (int r = 0; r < 3; ++r)
            #pragma unroll
            for (int s = 0; s < 3; ++s) {
                int xv = xp[r * W_IN + s];
                xv = xv < 0 ? 0 : (xv > 7 ? 7 : xv);
                acc += (float)xv * (float)(int)wp[r * 3 + s];
            }
    }
    out[idx] = acc;
}

extern "C" void kernel_launch(void* const* d_in, const int* in_sizes, int n_in,
                              void* d_out, int out_size, void* d_ws, size_t ws_size,
                              hipStream_t stream) {
    const int*   x = (const int*)d_in[0];
    const float* w = (const float*)d_in[1];
    float* out = (float*)d_out;

    const size_t need = XT_BYTES + WT_BYTES;   // ~26.3 MB
    if (ws_size >= need) {
        unsigned char* xt = (unsigned char*)d_ws;
        unsigned char* wt = (unsigned char*)((char*)d_ws + XT_BYTES);
        hipLaunchKernelGGL(xform, dim3(N_IMG * H_IN + K_OUT), dim3(256), 0, stream,
                           x, w, xt, wt);
        hipLaunchKernelGGL(conv_mfma, dim3(M_PIX / BM), dim3(512), 0, stream,
                           xt, wt, out);
    } else {
        const int total = N_IMG * K_OUT * HW_OUT;
        hipLaunchKernelGGL(conv_naive, dim3((total + 255) / 256), dim3(256), 0, stream, x, w, out);
    }
}